// Round 1
// baseline (224.943 us; speedup 1.0000x reference)
//
#include <hip/hip_runtime.h>

#define N_VOX 120000
#define C64 64
#define K27 27
#define VPW 8   // voxels per wave

// ---- prep: transpose nbr [N,27] -> nbrT [27,N] (coalesced writes per k) ----
__global__ void transpose_nbr_kernel(const int* __restrict__ nbr, int* __restrict__ nbrT) {
    int n = blockIdx.x * blockDim.x + threadIdx.x;
    if (n >= N_VOX) return;
#pragma unroll
    for (int k = 0; k < K27; ++k) {
        nbrT[k * N_VOX + n] = nbr[n * K27 + k];
    }
}

// ---- prep: fold BN params into scale/shift: y = x*s + sh ----
__global__ void bn_prep_kernel(const float* __restrict__ g1, const float* __restrict__ b1,
                               const float* __restrict__ m1, const float* __restrict__ v1,
                               const float* __restrict__ g2, const float* __restrict__ b2,
                               const float* __restrict__ m2, const float* __restrict__ v2,
                               float* __restrict__ p) {
    int i = threadIdx.x;  // 64 threads
    if (i >= C64) return;
    float s1 = g1[i] * rsqrtf(v1[i] + 1e-5f);
    p[0 * C64 + i] = s1;
    p[1 * C64 + i] = b1[i] - m1[i] * s1;
    float s2 = g2[i] * rsqrtf(v2[i] + 1e-5f);
    p[2 * C64 + i] = s2;
    p[3 * C64 + i] = b2[i] - m2[i] * s2;
}

// ---- main conv: one wave handles VPW voxels; lane = output channel d ----
// out[n,d] = relu( (sum_k sum_c f[nbr[n,k],c] * W[k,c,d]) * sc[d] + sh[d] (+ resid[n,d]) )
template <bool RESID>
__global__ __launch_bounds__(256) void conv_bn_relu_kernel(
    const float* __restrict__ fin,    // [N, 64]
    const int*   __restrict__ nbrT,   // [27, N]
    const float* __restrict__ W,      // [27, 64, 64]  (k, c_in, c_out)
    const float* __restrict__ sc,     // [64]
    const float* __restrict__ sh,     // [64]
    const float* __restrict__ resid,  // [N, 64] or unused
    float* __restrict__ out)          // [N, 64]
{
    const int lane = threadIdx.x & 63;
    int wid = (blockIdx.x * (blockDim.x >> 6)) + (threadIdx.x >> 6);
    wid = __builtin_amdgcn_readfirstlane(wid);
    const int n0 = wid * VPW;
    if (n0 >= N_VOX) return;

    float acc[VPW];
#pragma unroll
    for (int v = 0; v < VPW; ++v) acc[v] = 0.f;

    for (int k = 0; k < K27; ++k) {
        const int* nrow = nbrT + k * N_VOX + n0;   // uniform address
        int idx[VPW];
        int any = 0;
#pragma unroll
        for (int v = 0; v < VPW; ++v) {
            idx[v] = nrow[v];
            any |= (idx[v] >= 0) ? 1 : 0;
        }
        if (!any) continue;   // wave-uniform skip (~93% of k!=13 iterations)

        // Load W row-block for this k: w[c] = W[k][c][lane]  (coalesced per c)
        const float* Wk = W + k * (C64 * C64) + lane;
        float w[C64];
#pragma unroll
        for (int c = 0; c < C64; ++c) w[c] = Wk[c * C64];

#pragma unroll
        for (int v = 0; v < VPW; ++v) {
            if (idx[v] < 0) continue;              // uniform branch
            const float4* frow = (const float4*)(fin + (size_t)idx[v] * C64);
#pragma unroll
            for (int c4 = 0; c4 < C64 / 4; ++c4) {
                float4 fq = frow[c4];              // uniform 16B load (broadcast)
                acc[v] = fmaf(fq.x, w[c4 * 4 + 0], acc[v]);
                acc[v] = fmaf(fq.y, w[c4 * 4 + 1], acc[v]);
                acc[v] = fmaf(fq.z, w[c4 * 4 + 2], acc[v]);
                acc[v] = fmaf(fq.w, w[c4 * 4 + 3], acc[v]);
            }
        }
    }

    const float s = sc[lane];
    const float b = sh[lane];
#pragma unroll
    for (int v = 0; v < VPW; ++v) {
        const int n = n0 + v;
        float o = fmaf(acc[v], s, b);
        if (RESID) o += resid[(size_t)n * C64 + lane];
        o = fmaxf(o, 0.f);
        out[(size_t)n * C64 + lane] = o;
    }
}

extern "C" void kernel_launch(void* const* d_in, const int* in_sizes, int n_in,
                              void* d_out, int out_size, void* d_ws, size_t ws_size,
                              hipStream_t stream) {
    // setup_inputs order: features, W1, g1, b1, m1, v1, W2, g2, b2, m2, v2, nbr_idx
    const float* f   = (const float*)d_in[0];
    const float* W1  = (const float*)d_in[1];
    const float* g1  = (const float*)d_in[2];
    const float* b1  = (const float*)d_in[3];
    const float* m1  = (const float*)d_in[4];
    const float* v1  = (const float*)d_in[5];
    const float* W2  = (const float*)d_in[6];
    const float* g2  = (const float*)d_in[7];
    const float* b2  = (const float*)d_in[8];
    const float* m2  = (const float*)d_in[9];
    const float* v2  = (const float*)d_in[10];
    const int*   nbr = (const int*)d_in[11];
    float* out = (float*)d_out;

    // workspace layout
    char* ws = (char*)d_ws;
    int*   nbrT = (int*)ws;                                   // 27*N*4 = ~12.96 MB
    float* bnp  = (float*)(ws + (size_t)K27 * N_VOX * 4);     // 4*64*4 = 1 KB
    float* mid  = (float*)(ws + (size_t)K27 * N_VOX * 4 + 1024);  // N*64*4 = ~30.7 MB

    transpose_nbr_kernel<<<(N_VOX + 255) / 256, 256, 0, stream>>>(nbr, nbrT);
    bn_prep_kernel<<<1, 64, 0, stream>>>(g1, b1, m1, v1, g2, b2, m2, v2, bnp);

    const int waves  = (N_VOX + VPW - 1) / VPW;        // 15000
    const int blocks = (waves + 3) / 4;                // 4 waves / 256-thread block

    conv_bn_relu_kernel<false><<<blocks, 256, 0, stream>>>(
        f, nbrT, W1, bnp + 0 * C64, bnp + 1 * C64, nullptr, mid);
    conv_bn_relu_kernel<true><<<blocks, 256, 0, stream>>>(
        mid, nbrT, W2, bnp + 2 * C64, bnp + 3 * C64, f, out);
}